// Round 5
// baseline (1445.398 us; speedup 1.0000x reference)
//
#include <hip/hip_runtime.h>

#define N_NODES 20000
#define N_EDGES 640000

// ---------------- k0: zero flags + histogram counters ----------------
__global__ void k0_zero(float4* __restrict__ p, int n4){
    int i = blockIdx.x*blockDim.x + threadIdx.x;
    int stride = gridDim.x*blockDim.x;
    float4 z; z.x=0.f; z.y=0.f; z.z=0.f; z.w=0.f;
    for (; i<n4; i+=stride) p[i] = z;
}

// ---------------- kD: detect int32 vs int64 index buffers ----------------
__global__ void kD_detect(const int* __restrict__ eidx_w, const int* __restrict__ ety_w,
                          int* __restrict__ flags){
    int i = blockIdx.x*blockDim.x + threadIdx.x;
    int stride = gridDim.x*blockDim.x;
    int a0 = 0, a1 = 0;
    for (int w = 2*i+1; w < 2*N_EDGES; w += 2*stride) a0 |= eidx_w[w];
    for (int w = 2*i+1; w < N_EDGES;   w += 2*stride) a1 |= ety_w[w];
    if (a0) atomicOr(&flags[0], 1);
    if (a1) atomicOr(&flags[1], 1);
}

// ---------------- kN: normalize indices + fused dst histogram ----------------
__global__ void kN_norm(const int* __restrict__ eidx_w, const int* __restrict__ ety_w,
                        const int* __restrict__ flags,
                        int* __restrict__ dst, int* __restrict__ srcty,
                        int* __restrict__ cnt){
    int i = blockIdx.x*blockDim.x + threadIdx.x;
    int stride = gridDim.x*blockDim.x;
    const bool e32 = (flags[0] != 0);
    const bool t32 = (flags[1] != 0);
    for (int e = i; e < N_EDGES; e += stride){
        int s, d, t;
        if (e32){ s = eidx_w[e];   d = eidx_w[N_EDGES + e]; }
        else    { s = eidx_w[2*e]; d = eidx_w[2*N_EDGES + 2*e]; }
        t = t32 ? ety_w[e] : ety_w[2*e];
        s = min(max(s, 0), N_NODES-1);
        d = min(max(d, 0), N_NODES-1);
        t = min(max(t, 0), 15);
        dst[e] = d; srcty[e] = s | (t << 20);
        atomicAdd(&cnt[d], 1);
    }
}

// ---------------- kS: exclusive scan via shfl -> row_ptr, cursor ----------------
__global__ __launch_bounds__(1024) void kS_scan(const int* __restrict__ cnt,
                                                int* __restrict__ row_ptr,
                                                int* __restrict__ cursor){
    __shared__ int sW[16];
    __shared__ int sWS[16];
    __shared__ int sbase;
    const int t = threadIdx.x, lane = t & 63, wv = t >> 6;
    if (t==0) sbase = 0;
    __syncthreads();
    for (int base=0; base<N_NODES; base+=1024){
        int idx = base + t;
        int v = (idx<N_NODES) ? cnt[idx] : 0;
        int xs = v;
        #pragma unroll
        for (int off=1; off<64; off<<=1){
            int y = __shfl_up(xs, off, 64);
            if (lane >= off) xs += y;
        }
        if (lane==63) sW[wv] = xs;
        __syncthreads();
        if (t < 16){
            int wvv = sW[t], ws = wvv;
            #pragma unroll
            for (int off=1; off<16; off<<=1){
                int y = __shfl_up(ws, off, 16);
                if ((t&15) >= off) ws += y;
            }
            sWS[t] = ws - wvv;   // exclusive wave prefix
        }
        __syncthreads();
        int excl = sbase + sWS[wv] + xs - v;
        if (idx < N_NODES){ row_ptr[idx] = excl; cursor[idx] = excl; }
        __syncthreads();
        if (t==0) sbase += sWS[15] + sW[15];
        __syncthreads();
    }
    if (t==0) row_ptr[N_NODES] = sbase;
}

// ---------------- kC: scatter edges into CSR order (packed int2) ----------------
__global__ void kC_scatter(const int* __restrict__ dst, const int* __restrict__ srcty,
                           int* __restrict__ cursor, int2* __restrict__ eidty){
    int i = blockIdx.x*blockDim.x + threadIdx.x;
    int stride = gridDim.x*blockDim.x;
    for (int e = i; e < N_EDGES; e += stride){
        int pos = atomicAdd(&cursor[dst[e]], 1);
        eidty[pos] = make_int2(e, srcty[e]);
    }
}

// ---------------- kM: M[d][h] = sum_c gatW[d,h*16+c]*a_edge[h,c]; AT[ty][h] ----------------
__global__ __launch_bounds__(256) void kM_pre(const float* __restrict__ gat_edge_W,
                                              const float* __restrict__ a_edge,
                                              const float* __restrict__ gat_emb,
                                              float* __restrict__ Mw, float* __restrict__ ATw){
    __shared__ float sM[32*8];
    const int t = threadIdx.x;
    const int d = t>>3, hh = t&7;
    float acc = 0.f;
    #pragma unroll
    for (int c=0;c<16;c++) acc += gat_edge_W[d*128 + hh*16 + c]*a_edge[hh*16 + c];
    sM[d*8+hh] = acc; Mw[d*8+hh] = acc;
    __syncthreads();
    if (t < 128){
        int tyv = t>>3, h2 = t&7;
        float a = 0.f;
        #pragma unroll
        for (int dd=0;dd<32;dd++) a += gat_emb[tyv*32+dd]*sM[dd*8+h2];
        ATw[tyv*8+h2] = a;
    }
}

// ---------------- kT: T[ty][j] = gine_emb[ty]@gine_edge_W + gine_edge_b ----------------
__global__ __launch_bounds__(128) void kT_pre(const float* __restrict__ gine_emb,
                                              const float* __restrict__ gine_edge_W,
                                              const float* __restrict__ gine_edge_b,
                                              float* __restrict__ Tw){
    const int tyv = blockIdx.x;
    const int j = threadIdx.x;
    float acc = gine_edge_b[j];
    #pragma unroll
    for (int d=0;d<32;d++) acc += gine_emb[tyv*32+d]*gine_edge_W[d*128+j];
    Tw[tyv*128+j] = acc;
}

// ---------------- k1: h = x@gat_W (8 nodes/block), a_s, a_d ----------------
__global__ __launch_bounds__(128) void k1_node_prep(
    const float* __restrict__ x, const float* __restrict__ gat_W,
    const float* __restrict__ a_src, const float* __restrict__ a_dst,
    float* __restrict__ h_out, float* __restrict__ as_out, float* __restrict__ ad_out)
{
    __shared__ float sX[8][128];
    const int t = threadIdx.x;
    const int base = blockIdx.x*8;
    const float4* xin = (const float4*)(x + (size_t)base*128);
    float4* sx4 = (float4*)&sX[0][0];
    for (int i=t;i<256;i+=128) sx4[i] = xin[i];
    __syncthreads();
    float acc[8] = {0,0,0,0,0,0,0,0};
    for (int k=0;k<128;k++){
        float w = gat_W[k*128 + t];
        #pragma unroll
        for (int nn=0;nn<8;nn++) acc[nn] += sX[nn][k]*w;
    }
    const float asv = a_src[t], advv = a_dst[t];
    #pragma unroll
    for (int nn=0;nn<8;nn++){
        const int n = base + nn;
        h_out[(size_t)n*128 + t] = acc[nn];
        float vs = acc[nn]*asv, vd = acc[nn]*advv;
        #pragma unroll
        for (int off=8; off>=1; off>>=1){ vs += __shfl_xor(vs,off,16); vd += __shfl_xor(vd,off,16); }
        if ((t&15)==0){ as_out[n*8 + (t>>4)] = vs; ad_out[n*8 + (t>>4)] = vd; }
    }
}

// ---------------- k3: persistent per-node CSR aggregation ----------------
#define K3_BLOCKS 1024
__global__ __launch_bounds__(256, 4) void k3_csr(
    const float* __restrict__ x, const float* __restrict__ h, const float* __restrict__ eattr,
    const float* __restrict__ a_s, const float* __restrict__ a_d,
    const int* __restrict__ row_ptr, const int2* __restrict__ eidty,
    const float* __restrict__ Mw, const float* __restrict__ ATw, const float* __restrict__ Tw,
    const float* __restrict__ gine_W,
    float* __restrict__ agg, float* __restrict__ gacc)
{
    __shared__ float sT[16*128];
    __shared__ float sAT[16*8];
    const int t = threadIdx.x;
    const int half = t >> 7;        // two independent 128-thread node slots
    const int j = t & 127;
    const int hh = j >> 4;
    const int lane31 = t & 31;
    for (int i=t;i<2048;i+=256) sT[i]=Tw[i];
    if (t<128) sAT[t]=ATw[t];
    float wcol[32], mcol[32];
    #pragma unroll
    for (int k=0;k<32;k++){ wcol[k]=gine_W[k*128 + j]; mcol[k]=Mw[k*8 + hh]; }
    __syncthreads();

    for (int d = blockIdx.x*2 + half; d < N_NODES; d += gridDim.x*2){
        const float adv = a_d[d*8 + hh];
        const int row = row_ptr[d], end = row_ptr[d+1];
        float accA = 0.f, accG = 0.f, ps = 0.f;
        int i = row;
        for (; i+3 < end; i += 4){
            int2 r0 = eidty[i],   r1 = eidty[i+1];
            int2 r2 = eidty[i+2], r3 = eidty[i+3];
            int s0 = r0.y & 0xFFFFF, t0 = ((unsigned)r0.y)>>20;
            int s1 = r1.y & 0xFFFFF, t1 = ((unsigned)r1.y)>>20;
            int s2 = r2.y & 0xFFFFF, t2 = ((unsigned)r2.y)>>20;
            int s3 = r3.y & 0xFFFFF, t3 = ((unsigned)r3.y)>>20;
            float ev0 = eattr[(size_t)r0.x*32 + lane31];
            float ev1 = eattr[(size_t)r1.x*32 + lane31];
            float ev2 = eattr[(size_t)r2.x*32 + lane31];
            float ev3 = eattr[(size_t)r3.x*32 + lane31];
            float xv0 = x[(size_t)s0*128 + j], hv0 = h[(size_t)s0*128 + j];
            float xv1 = x[(size_t)s1*128 + j], hv1 = h[(size_t)s1*128 + j];
            float xv2 = x[(size_t)s2*128 + j], hv2 = h[(size_t)s2*128 + j];
            float xv3 = x[(size_t)s3*128 + j], hv3 = h[(size_t)s3*128 + j];
            float as0 = a_s[s0*8 + hh], as1 = a_s[s1*8 + hh];
            float as2 = a_s[s2*8 + hh], as3 = a_s[s3*8 + hh];
            float aE0=0.f, aE1=0.f, aE2=0.f, aE3=0.f;
            float ae0=0.f, ae1=0.f, ae2=0.f, ae3=0.f;
            #pragma unroll
            for (int k=0;k<32;k++){
                float v0 = __shfl(ev0, k, 64);
                float v1 = __shfl(ev1, k, 64);
                float v2 = __shfl(ev2, k, 64);
                float v3 = __shfl(ev3, k, 64);
                aE0 += v0*wcol[k]; ae0 += v0*mcol[k];
                aE1 += v1*wcol[k]; ae1 += v1*mcol[k];
                aE2 += v2*wcol[k]; ae2 += v2*mcol[k];
                aE3 += v3*wcol[k]; ae3 += v3*mcol[k];
            }
            float ep0 = aE0 + sT[t0*128 + j], ep1 = aE1 + sT[t1*128 + j];
            float ep2 = aE2 + sT[t2*128 + j], ep3 = aE3 + sT[t3*128 + j];
            float lg0 = as0 + adv + ae0 + sAT[t0*8 + hh];
            float lg1 = as1 + adv + ae1 + sAT[t1*8 + hh];
            float lg2 = as2 + adv + ae2 + sAT[t2*8 + hh];
            float lg3 = as3 + adv + ae3 + sAT[t3*8 + hh];
            lg0 = (lg0>0.f)?lg0:0.2f*lg0;  lg1 = (lg1>0.f)?lg1:0.2f*lg1;
            lg2 = (lg2>0.f)?lg2:0.2f*lg2;  lg3 = (lg3>0.f)?lg3:0.2f*lg3;
            float p0=__expf(lg0), p1=__expf(lg1), p2=__expf(lg2), p3=__expf(lg3);
            accA += fmaxf(xv0+ep0,0.f)+fmaxf(xv1+ep1,0.f)+fmaxf(xv2+ep2,0.f)+fmaxf(xv3+ep3,0.f);
            accG += p0*hv0 + p1*hv1 + p2*hv2 + p3*hv3;
            ps   += p0 + p1 + p2 + p3;
        }
        for (; i < end; i++){
            int2 r0 = eidty[i];
            int s0 = r0.y & 0xFFFFF, t0 = ((unsigned)r0.y)>>20;
            float ev0 = eattr[(size_t)r0.x*32 + lane31];
            float xv0 = x[(size_t)s0*128 + j], hv0 = h[(size_t)s0*128 + j];
            float as0 = a_s[s0*8 + hh];
            float aE0=0.f, ae0=0.f;
            #pragma unroll
            for (int k=0;k<32;k++){
                float v0 = __shfl(ev0, k, 64);
                aE0 += v0*wcol[k]; ae0 += v0*mcol[k];
            }
            float ep0 = aE0 + sT[t0*128 + j];
            float lg0 = as0 + adv + ae0 + sAT[t0*8 + hh];
            lg0 = (lg0>0.f)?lg0:0.2f*lg0;
            float p0 = __expf(lg0);
            accA += fmaxf(xv0+ep0,0.f);
            accG += p0*hv0;
            ps   += p0;
        }
        agg[(size_t)d*128 + j]  = accA;
        gacc[(size_t)d*128 + j] = accG / (ps + 1e-16f);
    }
}

// ---------------- k4: final node kernel (GINE MLP + comb + LN + ReLU) ----------------
#define NPB 4
__global__ __launch_bounds__(256) void k4_final(
    const float* __restrict__ x, const float* __restrict__ agg, const float* __restrict__ gat_acc,
    const float* __restrict__ gat_b, const float* __restrict__ eps_p,
    const float* __restrict__ W1, const float* __restrict__ b1,
    const float* __restrict__ W2, const float* __restrict__ gb2,
    const float* __restrict__ comb_W, const float* __restrict__ comb_b,
    const float* __restrict__ ln_g, const float* __restrict__ ln_b,
    float* __restrict__ out)
{
    __shared__ float sZt[256][NPB];     // transposed concat input
    __shared__ float sH2[2][128];
    __shared__ float sT1[2][128];
    __shared__ float sP1[4], sP2[4];
    __shared__ float sMu, sRs;
    const int t = threadIdx.x;
    const int half = t >> 7;
    const int j = t & 127;
    const float epsv = 1.f + eps_p[0];

    for (int pp=0; pp<NPB; pp+=2){
        const int nn = pp + half;
        const int n = blockIdx.x*NPB + nn;
        sH2[half][j] = epsv*x[(size_t)n*128 + j] + agg[(size_t)n*128 + j];
        sZt[j][nn] = gat_acc[(size_t)n*128 + j] + gat_b[j];
        __syncthreads();
        float acc = b1[j];
        #pragma unroll 8
        for (int k=0;k<128;k++) acc += sH2[half][k]*W1[k*128 + j];
        sT1[half][j] = fmaxf(acc, 0.f);
        __syncthreads();
        float acc2 = gb2[j];
        #pragma unroll 8
        for (int k=0;k<128;k++) acc2 += sT1[half][k]*W2[k*128 + j];
        sZt[128 + j][nn] = acc2;
        __syncthreads();
    }

    float z[NPB];
    const float cb = comb_b[t];
    #pragma unroll
    for (int nn=0;nn<NPB;nn++) z[nn] = cb;
    for (int k=0;k<256;k++){
        float w = comb_W[k*256 + t];
        float4 zi = *(const float4*)&sZt[k][0];
        z[0] += zi.x*w; z[1] += zi.y*w; z[2] += zi.z*w; z[3] += zi.w*w;
    }

    const float g  = ln_g[t];
    const float bb = ln_b[t];
    for (int nn=0;nn<NPB;nn++){
        const int n = blockIdx.x*NPB + nn;
        float zv = z[nn];
        float s1 = zv, s2 = zv*zv;
        #pragma unroll
        for (int off=32; off>=1; off>>=1){ s1 += __shfl_xor(s1,off,64); s2 += __shfl_xor(s2,off,64); }
        if ((t&63)==0){ sP1[t>>6]=s1; sP2[t>>6]=s2; }
        __syncthreads();
        if (t==0){
            float a1 = sP1[0]+sP1[1]+sP1[2]+sP1[3];
            float a2 = sP2[0]+sP2[1]+sP2[2]+sP2[3];
            float mu = a1*(1.f/256.f);
            float var = a2*(1.f/256.f) - mu*mu;
            sMu = mu; sRs = rsqrtf(var + 1e-5f);
        }
        __syncthreads();
        float r = (zv - sMu)*sRs*g + bb;
        out[(size_t)n*256 + t] = fmaxf(r, 0.f);
        __syncthreads();
    }
}

extern "C" void kernel_launch(void* const* d_in, const int* in_sizes, int n_in,
                              void* d_out, int out_size, void* d_ws, size_t ws_size,
                              hipStream_t stream)
{
    (void)in_sizes; (void)n_in; (void)out_size; (void)ws_size;
    const float* x           = (const float*)d_in[0];
    const int*   eidx_w      = (const int*)  d_in[1];
    const float* eattr       = (const float*)d_in[2];
    const int*   ety_w       = (const int*)  d_in[3];
    const float* gat_W       = (const float*)d_in[4];
    const float* gat_b       = (const float*)d_in[5];
    const float* gat_edge_W  = (const float*)d_in[6];
    const float* a_src       = (const float*)d_in[7];
    const float* a_dst       = (const float*)d_in[8];
    const float* a_edge      = (const float*)d_in[9];
    const float* gat_emb     = (const float*)d_in[10];
    const float* gine_emb    = (const float*)d_in[11];
    const float* gine_edge_W = (const float*)d_in[12];
    const float* gine_edge_b = (const float*)d_in[13];
    const float* gine_eps    = (const float*)d_in[14];
    const float* W1          = (const float*)d_in[15];
    const float* b1          = (const float*)d_in[16];
    const float* W2          = (const float*)d_in[17];
    const float* gb2         = (const float*)d_in[18];
    const float* comb_W      = (const float*)d_in[19];
    const float* comb_b      = (const float*)d_in[20];
    const float* ln_g        = (const float*)d_in[21];
    const float* ln_b        = (const float*)d_in[22];
    float* out = (float*)d_out;

    char* ws = (char*)d_ws;
    size_t off = 0;
    auto alloc = [&](size_t bytes)->void*{ void* p = ws + off; off += (bytes + 255)/256*256; return p; };
    size_t zero_start = off;
    int*   flags  = (int*)  alloc(256);
    int*   cnt    = (int*)  alloc((size_t)N_NODES*4);
    size_t zero_bytes = off - zero_start;
    int*   dstA   = (int*)  alloc((size_t)N_EDGES*4);
    int*   stA    = (int*)  alloc((size_t)N_EDGES*4);
    int*   rowp   = (int*)  alloc((size_t)(N_NODES+1)*4);
    int*   cursor = (int*)  alloc((size_t)N_NODES*4);
    int2*  eidty  = (int2*) alloc((size_t)N_EDGES*8);
    float* hws    = (float*)alloc((size_t)N_NODES*128*4);
    float* a_s    = (float*)alloc((size_t)N_NODES*8*4);
    float* a_d    = (float*)alloc((size_t)N_NODES*8*4);
    float* Mw     = (float*)alloc(32*8*4);
    float* ATw    = (float*)alloc(16*8*4);
    float* Tw     = (float*)alloc(16*128*4);
    float* agg    = (float*)alloc((size_t)N_NODES*128*4);
    float* gacc   = (float*)alloc((size_t)N_NODES*128*4);

    int n4 = (int)(zero_bytes/16);
    k0_zero<<<(n4+255)/256, 256, 0, stream>>>((float4*)(ws + zero_start), n4);
    kD_detect<<<512, 256, 0, stream>>>(eidx_w, ety_w, flags);
    kN_norm<<<1024, 256, 0, stream>>>(eidx_w, ety_w, flags, dstA, stA, cnt);
    kS_scan<<<1, 1024, 0, stream>>>(cnt, rowp, cursor);
    kC_scatter<<<1024, 256, 0, stream>>>(dstA, stA, cursor, eidty);

    kM_pre<<<1, 256, 0, stream>>>(gat_edge_W, a_edge, gat_emb, Mw, ATw);
    kT_pre<<<16, 128, 0, stream>>>(gine_emb, gine_edge_W, gine_edge_b, Tw);
    k1_node_prep<<<N_NODES/8, 128, 0, stream>>>(x, gat_W, a_src, a_dst, hws, a_s, a_d);

    k3_csr<<<K3_BLOCKS, 256, 0, stream>>>(x, hws, eattr, a_s, a_d, rowp, eidty,
                                          Mw, ATw, Tw, gine_edge_W, agg, gacc);

    k4_final<<<N_NODES/NPB, 256, 0, stream>>>(x, agg, gacc, gat_b, gine_eps,
                                              W1, b1, W2, gb2, comb_W, comb_b,
                                              ln_g, ln_b, out);
}

// Round 6
// 692.350 us; speedup vs baseline: 2.0877x; 2.0877x over previous
//
#include <hip/hip_runtime.h>

#define N_NODES 20000
#define N_EDGES 640000

// ---------------- k0: zero flags + histogram counters ----------------
__global__ void k0_zero(float4* __restrict__ p, int n4){
    int i = blockIdx.x*blockDim.x + threadIdx.x;
    int stride = gridDim.x*blockDim.x;
    float4 z; z.x=0.f; z.y=0.f; z.z=0.f; z.w=0.f;
    for (; i<n4; i+=stride) p[i] = z;
}

// ---------------- kD: detect int32 vs int64 index buffers ----------------
__global__ void kD_detect(const int* __restrict__ eidx_w, const int* __restrict__ ety_w,
                          int* __restrict__ flags){
    int i = blockIdx.x*blockDim.x + threadIdx.x;
    int stride = gridDim.x*blockDim.x;
    int a0 = 0, a1 = 0;
    for (int w = 2*i+1; w < 2*N_EDGES; w += 2*stride) a0 |= eidx_w[w];
    for (int w = 2*i+1; w < N_EDGES;   w += 2*stride) a1 |= ety_w[w];
    if (a0) atomicOr(&flags[0], 1);
    if (a1) atomicOr(&flags[1], 1);
}

// ---------------- kN: normalize indices + fused dst histogram ----------------
__global__ void kN_norm(const int* __restrict__ eidx_w, const int* __restrict__ ety_w,
                        const int* __restrict__ flags,
                        int* __restrict__ dst, int* __restrict__ srcty,
                        int* __restrict__ cnt){
    int i = blockIdx.x*blockDim.x + threadIdx.x;
    int stride = gridDim.x*blockDim.x;
    const bool e32 = (flags[0] != 0);
    const bool t32 = (flags[1] != 0);
    for (int e = i; e < N_EDGES; e += stride){
        int s, d, t;
        if (e32){ s = eidx_w[e];   d = eidx_w[N_EDGES + e]; }
        else    { s = eidx_w[2*e]; d = eidx_w[2*N_EDGES + 2*e]; }
        t = t32 ? ety_w[e] : ety_w[2*e];
        s = min(max(s, 0), N_NODES-1);
        d = min(max(d, 0), N_NODES-1);
        t = min(max(t, 0), 15);
        dst[e] = d; srcty[e] = s | (t << 20);
        atomicAdd(&cnt[d], 1);
    }
}

// ---------------- kS: exclusive scan via shfl -> row_ptr, cursor ----------------
__global__ __launch_bounds__(1024) void kS_scan(const int* __restrict__ cnt,
                                                int* __restrict__ row_ptr,
                                                int* __restrict__ cursor){
    __shared__ int sW[16];
    __shared__ int sWS[16];
    __shared__ int sbase;
    const int t = threadIdx.x, lane = t & 63, wv = t >> 6;
    if (t==0) sbase = 0;
    __syncthreads();
    for (int base=0; base<N_NODES; base+=1024){
        int idx = base + t;
        int v = (idx<N_NODES) ? cnt[idx] : 0;
        int xs = v;
        #pragma unroll
        for (int off=1; off<64; off<<=1){
            int y = __shfl_up(xs, off, 64);
            if (lane >= off) xs += y;
        }
        if (lane==63) sW[wv] = xs;
        __syncthreads();
        if (t < 16){
            int wvv = sW[t], ws = wvv;
            #pragma unroll
            for (int off=1; off<16; off<<=1){
                int y = __shfl_up(ws, off, 16);
                if ((t&15) >= off) ws += y;
            }
            sWS[t] = ws - wvv;
        }
        __syncthreads();
        int excl = sbase + sWS[wv] + xs - v;
        if (idx < N_NODES){ row_ptr[idx] = excl; cursor[idx] = excl; }
        __syncthreads();
        if (t==0) sbase += sWS[15] + sW[15];
        __syncthreads();
    }
    if (t==0) row_ptr[N_NODES] = sbase;
}

// ---------------- kC: scatter edges into CSR order ----------------
__global__ void kC_scatter(const int* __restrict__ dst, const int* __restrict__ srcty,
                           int* __restrict__ cursor,
                           int* __restrict__ eid_s, int* __restrict__ sty_s,
                           int* __restrict__ dst_s){
    int i = blockIdx.x*blockDim.x + threadIdx.x;
    int stride = gridDim.x*blockDim.x;
    for (int e = i; e < N_EDGES; e += stride){
        int d = dst[e];
        int pos = atomicAdd(&cursor[d], 1);
        eid_s[pos] = e;
        sty_s[pos] = srcty[e];
        dst_s[pos] = d;
    }
}

// ---------------- kM: Mt[h][d] = sum_c gatW[d,h*16+c]*a_edge[h,c]; AT[ty][h] ----------------
__global__ __launch_bounds__(256) void kM_pre(const float* __restrict__ gat_edge_W,
                                              const float* __restrict__ a_edge,
                                              const float* __restrict__ gat_emb,
                                              float* __restrict__ Mt, float* __restrict__ ATw){
    __shared__ float sM[32*8];
    const int t = threadIdx.x;
    const int d = t>>3, hh = t&7;
    float acc = 0.f;
    #pragma unroll
    for (int c=0;c<16;c++) acc += gat_edge_W[d*128 + hh*16 + c]*a_edge[hh*16 + c];
    sM[d*8+hh] = acc; Mt[hh*32 + d] = acc;
    __syncthreads();
    if (t < 128){
        int tyv = t>>3, h2 = t&7;
        float a = 0.f;
        #pragma unroll
        for (int dd=0;dd<32;dd++) a += gat_emb[tyv*32+dd]*sM[dd*8+h2];
        ATw[tyv*8+h2] = a;
    }
}

// ---------------- kT: T[ty][j] = gine_emb[ty]@gine_edge_W + gine_edge_b ----------------
__global__ __launch_bounds__(128) void kT_pre(const float* __restrict__ gine_emb,
                                              const float* __restrict__ gine_edge_W,
                                              const float* __restrict__ gine_edge_b,
                                              float* __restrict__ Tw){
    const int tyv = blockIdx.x;
    const int j = threadIdx.x;
    float acc = gine_edge_b[j];
    #pragma unroll
    for (int d=0;d<32;d++) acc += gine_emb[tyv*32+d]*gine_edge_W[d*128+j];
    Tw[tyv*128+j] = acc;
}

// ---------------- k1: h = x@gat_W (8 nodes/block), a_s, a_d ----------------
__global__ __launch_bounds__(128) void k1_node_prep(
    const float* __restrict__ x, const float* __restrict__ gat_W,
    const float* __restrict__ a_src, const float* __restrict__ a_dst,
    float* __restrict__ h_out, float* __restrict__ as_out, float* __restrict__ ad_out)
{
    __shared__ float sX[8][128];
    const int t = threadIdx.x;
    const int base = blockIdx.x*8;
    const float4* xin = (const float4*)(x + (size_t)base*128);
    float4* sx4 = (float4*)&sX[0][0];
    for (int i=t;i<256;i+=128) sx4[i] = xin[i];
    __syncthreads();
    float acc[8] = {0,0,0,0,0,0,0,0};
    for (int k=0;k<128;k++){
        float w = gat_W[k*128 + t];
        #pragma unroll
        for (int nn=0;nn<8;nn++) acc[nn] += sX[nn][k]*w;
    }
    const float asv = a_src[t], advv = a_dst[t];
    #pragma unroll
    for (int nn=0;nn<8;nn++){
        const int n = base + nn;
        h_out[(size_t)n*128 + t] = acc[nn];
        float vs = acc[nn]*asv, vd = acc[nn]*advv;
        #pragma unroll
        for (int off=8; off>=1; off>>=1){ vs += __shfl_xor(vs,off,16); vd += __shfl_xor(vd,off,16); }
        if ((t&15)==0){ as_out[n*8 + (t>>4)] = vs; ad_out[n*8 + (t>>4)] = vd; }
    }
}

__device__ __forceinline__ unsigned pack_bf2(float a, float b){
    unsigned ua = __float_as_uint(a), ub = __float_as_uint(b);
    ua = (ua + 0x7FFFu + ((ua>>16)&1u)) >> 16;
    ub = (ub + 0x7FFFu + ((ub>>16)&1u)) >> 16;
    return ua | (ub<<16);
}

// ---------------- kE: per-edge precompute — evb (bf16x2, CSR order) + p ----------------
__global__ __launch_bounds__(256) void kE_edge(
    const float* __restrict__ eattr,
    const int* __restrict__ eid_s, const int* __restrict__ sty_s, const int* __restrict__ dst_s,
    const float* __restrict__ a_s, const float* __restrict__ a_d,
    const float* __restrict__ Mt, const float* __restrict__ ATw,
    unsigned* __restrict__ evb, float* __restrict__ p_s)
{
    __shared__ float sEv[32][36];
    __shared__ float sMt[8][36];
    __shared__ float sAT[16*8];
    const int t = threadIdx.x;
    if (t < 256) sMt[t>>5][t&31] = Mt[t];
    if (t < 128) sAT[t] = ATw[t];
    const int et = t>>3, q = t&7;
    for (int base = blockIdx.x*32; base < N_EDGES; base += gridDim.x*32){
        __syncthreads();   // protects sEv from previous iteration's readers
        int e = eid_s[base + et];
        float4 f = ((const float4*)eattr)[(size_t)e*8 + q];
        *(float4*)&sEv[et][q*4] = f;
        ((uint2*)evb)[(size_t)(base+et)*8 + q] = make_uint2(pack_bf2(f.x,f.y), pack_bf2(f.z,f.w));
        __syncthreads();
        // compute p for (edge el, head hq)
        const int el = et, hq = q;
        float acc = 0.f;
        #pragma unroll
        for (int m=0;m<8;m++){
            float4 ev4 = *(const float4*)&sEv[el][m*4];
            float4 m4  = *(const float4*)&sMt[hq][m*4];
            acc += ev4.x*m4.x + ev4.y*m4.y + ev4.z*m4.z + ev4.w*m4.w;
        }
        int sty = sty_s[base+el];
        int srcn = sty & 0xFFFFF; int tyv = ((unsigned)sty)>>20;
        int dn = dst_s[base+el];
        float lg = a_s[srcn*8+hq] + a_d[dn*8+hq] + acc + sAT[tyv*8+hq];
        lg = (lg>0.f) ? lg : 0.2f*lg;
        p_s[(size_t)(base+el)*8 + hq] = __expf(lg);
    }
}

// ---------------- k3: persistent gather — 1 wave per node, 2 ch/thread ----------------
#define K3_BLOCKS 1024
__global__ __launch_bounds__(256, 2) void k3_gather(
    const float* __restrict__ x, const float* __restrict__ h,
    const unsigned* __restrict__ evb, const float* __restrict__ p_s,
    const int* __restrict__ sty_s, const int* __restrict__ row_ptr,
    const float* __restrict__ Tw, const float* __restrict__ gine_W,
    float* __restrict__ agg, float* __restrict__ gacc)
{
    __shared__ float sT[16*128];
    const int t = threadIdx.x;
    for (int i=t;i<2048;i+=256) sT[i]=Tw[i];
    const int lane = t & 63;
    const int wid = blockIdx.x*4 + (t>>6);
    const int j0 = lane, j1 = lane + 64;
    const int hh0 = lane>>4, hh1 = hh0 + 4;
    float w0[32], w1[32];
    #pragma unroll
    for (int k=0;k<32;k++){ w0[k]=gine_W[k*128 + j0]; w1[k]=gine_W[k*128 + j1]; }
    __syncthreads();

    for (int d = wid; d < N_NODES; d += K3_BLOCKS*4){
        const int row = row_ptr[d], end = row_ptr[d+1];
        float accA0=0.f, accA1=0.f, accG0=0.f, accG1=0.f, ps0=0.f, ps1=0.f;
        for (int pos = row; pos < end; pos++){
            int sty = sty_s[pos];
            int srcn = sty & 0xFFFFF;
            int ty = ((unsigned)sty)>>20;
            unsigned u = evb[(size_t)pos*16 + (lane&15)];
            float xv0 = x[(size_t)srcn*128 + j0], xv1 = x[(size_t)srcn*128 + j1];
            float hv0 = h[(size_t)srcn*128 + j0], hv1 = h[(size_t)srcn*128 + j1];
            float p0 = p_s[(size_t)pos*8 + hh0], p1 = p_s[(size_t)pos*8 + hh1];
            float ep0 = sT[ty*128 + j0], ep1 = sT[ty*128 + j1];
            #pragma unroll
            for (int m=0;m<16;m++){
                unsigned uu = __shfl(u, m, 64);
                float lo = __uint_as_float(uu << 16);
                float hi = __uint_as_float(uu & 0xFFFF0000u);
                ep0 += lo*w0[2*m] + hi*w0[2*m+1];
                ep1 += lo*w1[2*m] + hi*w1[2*m+1];
            }
            accA0 += fmaxf(xv0+ep0, 0.f);
            accA1 += fmaxf(xv1+ep1, 0.f);
            accG0 += p0*hv0; accG1 += p1*hv1;
            ps0 += p0; ps1 += p1;
        }
        agg[(size_t)d*128 + j0]  = accA0;
        agg[(size_t)d*128 + j1]  = accA1;
        gacc[(size_t)d*128 + j0] = accG0 / (ps0 + 1e-16f);
        gacc[(size_t)d*128 + j1] = accG1 / (ps1 + 1e-16f);
    }
}

// ---------------- k4: final node kernel (GINE MLP + comb + LN + ReLU) ----------------
#define NPB 4
__global__ __launch_bounds__(256) void k4_final(
    const float* __restrict__ x, const float* __restrict__ agg, const float* __restrict__ gat_acc,
    const float* __restrict__ gat_b, const float* __restrict__ eps_p,
    const float* __restrict__ W1, const float* __restrict__ b1,
    const float* __restrict__ W2, const float* __restrict__ gb2,
    const float* __restrict__ comb_W, const float* __restrict__ comb_b,
    const float* __restrict__ ln_g, const float* __restrict__ ln_b,
    float* __restrict__ out)
{
    __shared__ float sZt[256][NPB];
    __shared__ float sH2[2][128];
    __shared__ float sT1[2][128];
    __shared__ float sP1[4], sP2[4];
    __shared__ float sMu, sRs;
    const int t = threadIdx.x;
    const int half = t >> 7;
    const int j = t & 127;
    const float epsv = 1.f + eps_p[0];

    for (int pp=0; pp<NPB; pp+=2){
        const int nn = pp + half;
        const int n = blockIdx.x*NPB + nn;
        sH2[half][j] = epsv*x[(size_t)n*128 + j] + agg[(size_t)n*128 + j];
        sZt[j][nn] = gat_acc[(size_t)n*128 + j] + gat_b[j];
        __syncthreads();
        float acc = b1[j];
        #pragma unroll 8
        for (int k=0;k<128;k++) acc += sH2[half][k]*W1[k*128 + j];
        sT1[half][j] = fmaxf(acc, 0.f);
        __syncthreads();
        float acc2 = gb2[j];
        #pragma unroll 8
        for (int k=0;k<128;k++) acc2 += sT1[half][k]*W2[k*128 + j];
        sZt[128 + j][nn] = acc2;
        __syncthreads();
    }

    float z[NPB];
    const float cb = comb_b[t];
    #pragma unroll
    for (int nn=0;nn<NPB;nn++) z[nn] = cb;
    for (int k=0;k<256;k++){
        float w = comb_W[k*256 + t];
        float4 zi = *(const float4*)&sZt[k][0];
        z[0] += zi.x*w; z[1] += zi.y*w; z[2] += zi.z*w; z[3] += zi.w*w;
    }

    const float g  = ln_g[t];
    const float bb = ln_b[t];
    for (int nn=0;nn<NPB;nn++){
        const int n = blockIdx.x*NPB + nn;
        float zv = z[nn];
        float s1 = zv, s2 = zv*zv;
        #pragma unroll
        for (int off=32; off>=1; off>>=1){ s1 += __shfl_xor(s1,off,64); s2 += __shfl_xor(s2,off,64); }
        if ((t&63)==0){ sP1[t>>6]=s1; sP2[t>>6]=s2; }
        __syncthreads();
        if (t==0){
            float a1 = sP1[0]+sP1[1]+sP1[2]+sP1[3];
            float a2 = sP2[0]+sP2[1]+sP2[2]+sP2[3];
            float mu = a1*(1.f/256.f);
            float var = a2*(1.f/256.f) - mu*mu;
            sMu = mu; sRs = rsqrtf(var + 1e-5f);
        }
        __syncthreads();
        float r = (zv - sMu)*sRs*g + bb;
        out[(size_t)n*256 + t] = fmaxf(r, 0.f);
        __syncthreads();
    }
}

extern "C" void kernel_launch(void* const* d_in, const int* in_sizes, int n_in,
                              void* d_out, int out_size, void* d_ws, size_t ws_size,
                              hipStream_t stream)
{
    (void)in_sizes; (void)n_in; (void)out_size; (void)ws_size;
    const float* x           = (const float*)d_in[0];
    const int*   eidx_w      = (const int*)  d_in[1];
    const float* eattr       = (const float*)d_in[2];
    const int*   ety_w       = (const int*)  d_in[3];
    const float* gat_W       = (const float*)d_in[4];
    const float* gat_b       = (const float*)d_in[5];
    const float* gat_edge_W  = (const float*)d_in[6];
    const float* a_src       = (const float*)d_in[7];
    const float* a_dst       = (const float*)d_in[8];
    const float* a_edge      = (const float*)d_in[9];
    const float* gat_emb     = (const float*)d_in[10];
    const float* gine_emb    = (const float*)d_in[11];
    const float* gine_edge_W = (const float*)d_in[12];
    const float* gine_edge_b = (const float*)d_in[13];
    const float* gine_eps    = (const float*)d_in[14];
    const float* W1          = (const float*)d_in[15];
    const float* b1          = (const float*)d_in[16];
    const float* W2          = (const float*)d_in[17];
    const float* gb2         = (const float*)d_in[18];
    const float* comb_W      = (const float*)d_in[19];
    const float* comb_b      = (const float*)d_in[20];
    const float* ln_g        = (const float*)d_in[21];
    const float* ln_b        = (const float*)d_in[22];
    float* out = (float*)d_out;

    char* ws = (char*)d_ws;
    size_t off = 0;
    auto alloc = [&](size_t bytes)->void*{ void* p = ws + off; off += (bytes + 255)/256*256; return p; };
    size_t zero_start = off;
    int*      flags  = (int*)     alloc(256);
    int*      cnt    = (int*)     alloc((size_t)N_NODES*4);
    size_t zero_bytes = off - zero_start;
    int*      dstA   = (int*)     alloc((size_t)N_EDGES*4);
    int*      stA    = (int*)     alloc((size_t)N_EDGES*4);
    int*      rowp   = (int*)     alloc((size_t)(N_NODES+1)*4);
    int*      cursor = (int*)     alloc((size_t)N_NODES*4);
    int*      eid_s  = (int*)     alloc((size_t)N_EDGES*4);
    int*      sty_s  = (int*)     alloc((size_t)N_EDGES*4);
    int*      dst_s  = (int*)     alloc((size_t)N_EDGES*4);
    unsigned* evb    = (unsigned*)alloc((size_t)N_EDGES*64);
    float*    p_s    = (float*)   alloc((size_t)N_EDGES*8*4);
    float*    hws    = (float*)   alloc((size_t)N_NODES*128*4);
    float*    a_s    = (float*)   alloc((size_t)N_NODES*8*4);
    float*    a_d    = (float*)   alloc((size_t)N_NODES*8*4);
    float*    Mt     = (float*)   alloc(32*8*4);
    float*    ATw    = (float*)   alloc(16*8*4);
    float*    Tw     = (float*)   alloc(16*128*4);
    float*    agg    = (float*)   alloc((size_t)N_NODES*128*4);
    float*    gacc   = (float*)   alloc((size_t)N_NODES*128*4);

    int n4 = (int)(zero_bytes/16);
    k0_zero<<<(n4+255)/256, 256, 0, stream>>>((float4*)(ws + zero_start), n4);
    kD_detect<<<512, 256, 0, stream>>>(eidx_w, ety_w, flags);
    kN_norm<<<1024, 256, 0, stream>>>(eidx_w, ety_w, flags, dstA, stA, cnt);
    kS_scan<<<1, 1024, 0, stream>>>(cnt, rowp, cursor);
    kC_scatter<<<1024, 256, 0, stream>>>(dstA, stA, cursor, eid_s, sty_s, dst_s);

    kM_pre<<<1, 256, 0, stream>>>(gat_edge_W, a_edge, gat_emb, Mt, ATw);
    kT_pre<<<16, 128, 0, stream>>>(gine_emb, gine_edge_W, gine_edge_b, Tw);
    k1_node_prep<<<N_NODES/8, 128, 0, stream>>>(x, gat_W, a_src, a_dst, hws, a_s, a_d);

    kE_edge<<<2500, 256, 0, stream>>>(eattr, eid_s, sty_s, dst_s, a_s, a_d, Mt, ATw, evb, p_s);

    k3_gather<<<K3_BLOCKS, 256, 0, stream>>>(x, hws, evb, p_s, sty_s, rowp, Tw,
                                             gine_edge_W, agg, gacc);

    k4_final<<<N_NODES/NPB, 256, 0, stream>>>(x, agg, gacc, gat_b, gine_eps,
                                              W1, b1, W2, gb2, comb_W, comb_b,
                                              ln_g, ln_b, out);
}

// Round 7
// 628.000 us; speedup vs baseline: 2.3016x; 1.1025x over previous
//
#include <hip/hip_runtime.h>

#define N_NODES 20000
#define N_EDGES 640000

typedef _Float16 h2v __attribute__((ext_vector_type(2)));

__device__ __forceinline__ unsigned packh2(float a, float b){
    h2v v; v.x = (_Float16)a; v.y = (_Float16)b;
    return __builtin_bit_cast(unsigned, v);
}

#if __has_builtin(__builtin_amdgcn_fdot2)
__device__ __forceinline__ float fdot2f(h2v a, h2v b, float c){
    return __builtin_amdgcn_fdot2(a, b, c, false);
}
#else
__device__ __forceinline__ float fdot2f(h2v a, h2v b, float c){
    return c + (float)a.x*(float)b.x + (float)a.y*(float)b.y;
}
#endif

// ---------------- k0: zero flags + histogram counters ----------------
__global__ void k0_zero(float4* __restrict__ p, int n4){
    int i = blockIdx.x*blockDim.x + threadIdx.x;
    int stride = gridDim.x*blockDim.x;
    float4 z; z.x=0.f; z.y=0.f; z.z=0.f; z.w=0.f;
    for (; i<n4; i+=stride) p[i] = z;
}

// ---------------- kD: detect int32 vs int64 index buffers ----------------
__global__ void kD_detect(const int* __restrict__ eidx_w, const int* __restrict__ ety_w,
                          int* __restrict__ flags){
    int i = blockIdx.x*blockDim.x + threadIdx.x;
    int stride = gridDim.x*blockDim.x;
    int a0 = 0, a1 = 0;
    for (int w = 2*i+1; w < 2*N_EDGES; w += 2*stride) a0 |= eidx_w[w];
    for (int w = 2*i+1; w < N_EDGES;   w += 2*stride) a1 |= ety_w[w];
    if (a0) atomicOr(&flags[0], 1);
    if (a1) atomicOr(&flags[1], 1);
}

// ---------------- kN: normalize indices + fused dst histogram ----------------
__global__ void kN_norm(const int* __restrict__ eidx_w, const int* __restrict__ ety_w,
                        const int* __restrict__ flags,
                        int* __restrict__ dst, int* __restrict__ srcty,
                        int* __restrict__ cnt){
    int i = blockIdx.x*blockDim.x + threadIdx.x;
    int stride = gridDim.x*blockDim.x;
    const bool e32 = (flags[0] != 0);
    const bool t32 = (flags[1] != 0);
    for (int e = i; e < N_EDGES; e += stride){
        int s, d, t;
        if (e32){ s = eidx_w[e];   d = eidx_w[N_EDGES + e]; }
        else    { s = eidx_w[2*e]; d = eidx_w[2*N_EDGES + 2*e]; }
        t = t32 ? ety_w[e] : ety_w[2*e];
        s = min(max(s, 0), N_NODES-1);
        d = min(max(d, 0), N_NODES-1);
        t = min(max(t, 0), 15);
        dst[e] = d; srcty[e] = s | (t << 20);
        atomicAdd(&cnt[d], 1);
    }
}

// ---------------- kS: exclusive scan via shfl -> row_ptr, cursor ----------------
__global__ __launch_bounds__(1024) void kS_scan(const int* __restrict__ cnt,
                                                int* __restrict__ row_ptr,
                                                int* __restrict__ cursor){
    __shared__ int sW[16];
    __shared__ int sWS[16];
    __shared__ int sbase;
    const int t = threadIdx.x, lane = t & 63, wv = t >> 6;
    if (t==0) sbase = 0;
    __syncthreads();
    for (int base=0; base<N_NODES; base+=1024){
        int idx = base + t;
        int v = (idx<N_NODES) ? cnt[idx] : 0;
        int xs = v;
        #pragma unroll
        for (int off=1; off<64; off<<=1){
            int y = __shfl_up(xs, off, 64);
            if (lane >= off) xs += y;
        }
        if (lane==63) sW[wv] = xs;
        __syncthreads();
        if (t < 16){
            int wvv = sW[t], ws = wvv;
            #pragma unroll
            for (int off=1; off<16; off<<=1){
                int y = __shfl_up(ws, off, 16);
                if ((t&15) >= off) ws += y;
            }
            sWS[t] = ws - wvv;
        }
        __syncthreads();
        int excl = sbase + sWS[wv] + xs - v;
        if (idx < N_NODES){ row_ptr[idx] = excl; cursor[idx] = excl; }
        __syncthreads();
        if (t==0) sbase += sWS[15] + sW[15];
        __syncthreads();
    }
    if (t==0) row_ptr[N_NODES] = sbase;
}

// ---------------- kM: Mt[h][d] = sum_c gatW[d,h*16+c]*a_edge[h,c]; AT[ty][h] ----------------
__global__ __launch_bounds__(256) void kM_pre(const float* __restrict__ gat_edge_W,
                                              const float* __restrict__ a_edge,
                                              const float* __restrict__ gat_emb,
                                              float* __restrict__ Mt, float* __restrict__ ATw){
    __shared__ float sM[32*8];
    const int t = threadIdx.x;
    const int d = t>>3, hh = t&7;
    float acc = 0.f;
    #pragma unroll
    for (int c=0;c<16;c++) acc += gat_edge_W[d*128 + hh*16 + c]*a_edge[hh*16 + c];
    sM[d*8+hh] = acc; Mt[hh*32 + d] = acc;
    __syncthreads();
    if (t < 128){
        int tyv = t>>3, h2 = t&7;
        float a = 0.f;
        #pragma unroll
        for (int dd=0;dd<32;dd++) a += gat_emb[tyv*32+dd]*sM[dd*8+h2];
        ATw[tyv*8+h2] = a;
    }
}

// ---------------- kT: T[ty][j] = gine_emb[ty]@gine_edge_W + gine_edge_b ----------------
__global__ __launch_bounds__(128) void kT_pre(const float* __restrict__ gine_emb,
                                              const float* __restrict__ gine_edge_W,
                                              const float* __restrict__ gine_edge_b,
                                              float* __restrict__ Tw){
    const int tyv = blockIdx.x;
    const int j = threadIdx.x;
    float acc = gine_edge_b[j];
    #pragma unroll
    for (int d=0;d<32;d++) acc += gine_emb[tyv*32+d]*gine_edge_W[d*128+j];
    Tw[tyv*128+j] = acc;
}

// ---------------- k1: h = x@gat_W (8 nodes/block), pack xhb (f16x2), a_s, a_d ----------------
__global__ __launch_bounds__(128) void k1_node_prep(
    const float* __restrict__ x, const float* __restrict__ gat_W,
    const float* __restrict__ a_src, const float* __restrict__ a_dst,
    unsigned* __restrict__ xhb, float* __restrict__ as_out, float* __restrict__ ad_out)
{
    __shared__ float sX[8][128];
    __shared__ float sH[128];
    const int t = threadIdx.x;
    const int base = blockIdx.x*8;
    const float4* xin = (const float4*)(x + (size_t)base*128);
    float4* sx4 = (float4*)&sX[0][0];
    for (int i=t;i<256;i+=128) sx4[i] = xin[i];
    __syncthreads();
    float acc[8] = {0,0,0,0,0,0,0,0};
    for (int k=0;k<128;k++){
        float w = gat_W[k*128 + t];
        #pragma unroll
        for (int nn=0;nn<8;nn++) acc[nn] += sX[nn][k]*w;
    }
    const float asv = a_src[t], advv = a_dst[t];
    #pragma unroll
    for (int nn=0;nn<8;nn++){
        const int n = base + nn;
        float vs = acc[nn]*asv, vd = acc[nn]*advv;
        #pragma unroll
        for (int off=8; off>=1; off>>=1){ vs += __shfl_xor(vs,off,16); vd += __shfl_xor(vd,off,16); }
        if ((t&15)==0){ as_out[n*8 + (t>>4)] = vs; ad_out[n*8 + (t>>4)] = vd; }
        __syncthreads();               // protect sH from previous nn's readers
        sH[t] = acc[nn];
        __syncthreads();
        if (t < 64){
            xhb[(size_t)n*128 + t] = packh2(sX[nn][2*t], sX[nn][2*t+1]);
        } else {
            int i = t - 64;
            xhb[(size_t)n*128 + 64 + i] = packh2(sH[2*i], sH[2*i+1]);
        }
    }
}

// ---------------- kCE: fused CSR-scatter + edge precompute (evb f16x2, p) ----------------
__global__ __launch_bounds__(256) void kCE_edge(
    const float* __restrict__ eattr,
    const int* __restrict__ dstA, const int* __restrict__ styA,
    const float* __restrict__ a_s, const float* __restrict__ a_d,
    const float* __restrict__ Mt, const float* __restrict__ ATw,
    int* __restrict__ cursor,
    unsigned* __restrict__ evb, float* __restrict__ p_s, int* __restrict__ sty_s)
{
    __shared__ float sEv[32][36];
    __shared__ float sMt[8][36];
    __shared__ float sAT[16*8];
    __shared__ int sPos[32];
    const int t = threadIdx.x;
    sMt[t>>5][t&31] = Mt[t];
    if (t < 128) sAT[t] = ATw[t];
    const int et = t>>3, q = t&7;
    for (int base = blockIdx.x*32; base < N_EDGES; base += gridDim.x*32){
        __syncthreads();   // protect sEv/sPos from previous iteration's readers
        const int e = base + et;
        float4 f = ((const float4*)eattr)[(size_t)e*8 + q];
        *(float4*)&sEv[et][q*4] = f;
        const int d = dstA[e];
        const int sty = styA[e];
        if (q==0) sPos[et] = atomicAdd(&cursor[d], 1);
        __syncthreads();
        const int pos = sPos[et];
        ((uint2*)evb)[(size_t)pos*8 + q] = make_uint2(packh2(f.x,f.y), packh2(f.z,f.w));
        float acc = 0.f;
        #pragma unroll
        for (int m=0;m<8;m++){
            float4 ev4 = *(const float4*)&sEv[et][m*4];
            float4 m4  = *(const float4*)&sMt[q][m*4];
            acc += ev4.x*m4.x + ev4.y*m4.y + ev4.z*m4.z + ev4.w*m4.w;
        }
        const int srcn = sty & 0xFFFFF;
        const int tyv = ((unsigned)sty)>>20;
        float lg = a_s[srcn*8+q] + a_d[d*8+q] + acc + sAT[tyv*8+q];
        lg = (lg>0.f) ? lg : 0.2f*lg;
        p_s[(size_t)pos*8 + q] = __expf(lg);
        if (q==0) sty_s[pos] = sty;
    }
}

// ---------------- k3: persistent gather — 1 wave/node, channels (2l, 2l+1) ----------------
__global__ __launch_bounds__(256) void k3_gather(
    const unsigned* __restrict__ xhb, const unsigned* __restrict__ evb,
    const float* __restrict__ p_s, const int* __restrict__ sty_s,
    const int* __restrict__ row_ptr,
    const float* __restrict__ Tw, const float* __restrict__ gine_W,
    float* __restrict__ agg, float* __restrict__ gacc)
{
    __shared__ float sT[16*128];
    const int t = threadIdx.x;
    for (int i=t;i<2048;i+=256) sT[i]=Tw[i];
    const int lane = t & 63;
    const int j0 = 2*lane, j1 = j0 + 1;
    const int hh = lane >> 3;            // j0/16 == j1/16
    unsigned w0p[16], w1p[16];
    #pragma unroll
    for (int m=0;m<16;m++){
        w0p[m] = packh2(gine_W[(2*m)*128 + j0], gine_W[(2*m+1)*128 + j0]);
        w1p[m] = packh2(gine_W[(2*m)*128 + j1], gine_W[(2*m+1)*128 + j1]);
    }
    __syncthreads();
    const int nwaves = gridDim.x*4;
    for (int d = blockIdx.x*4 + (t>>6); d < N_NODES; d += nwaves){
        const int row = row_ptr[d], end = row_ptr[d+1];
        float accA0=0.f, accA1=0.f, accG0=0.f, accG1=0.f, ps=0.f;
        for (int pos = row; pos < end; pos++){
            const int sty = sty_s[pos];
            const int srcn = sty & 0xFFFFF;
            const int ty = ((unsigned)sty)>>20;
            unsigned u  = evb[(size_t)pos*16 + (lane&15)];
            unsigned xp = xhb[(size_t)srcn*128 + lane];
            unsigned hp = xhb[(size_t)srcn*128 + 64 + lane];
            float p = p_s[(size_t)pos*8 + hh];
            float2 tt = ((const float2*)sT)[ty*64 + lane];
            float ep0 = tt.x, ep1 = tt.y;
            #pragma unroll
            for (int m=0;m<16;m++){
                unsigned uu = __shfl(u, m, 64);
                h2v ev = __builtin_bit_cast(h2v, uu);
                ep0 = fdot2f(ev, __builtin_bit_cast(h2v, w0p[m]), ep0);
                ep1 = fdot2f(ev, __builtin_bit_cast(h2v, w1p[m]), ep1);
            }
            h2v xv = __builtin_bit_cast(h2v, xp);
            h2v hv = __builtin_bit_cast(h2v, hp);
            accA0 += fmaxf((float)xv.x + ep0, 0.f);
            accA1 += fmaxf((float)xv.y + ep1, 0.f);
            accG0 += p*(float)hv.x;
            accG1 += p*(float)hv.y;
            ps += p;
        }
        float inv = 1.f/(ps + 1e-16f);
        ((float2*)agg )[(size_t)d*64 + lane] = make_float2(accA0, accA1);
        ((float2*)gacc)[(size_t)d*64 + lane] = make_float2(accG0*inv, accG1*inv);
    }
}

// ---------------- k4: final node kernel (GINE MLP + comb + LN + ReLU) ----------------
#define NPB 8
__global__ __launch_bounds__(256) void k4_final(
    const float* __restrict__ x, const float* __restrict__ agg, const float* __restrict__ gat_acc,
    const float* __restrict__ gat_b, const float* __restrict__ eps_p,
    const float* __restrict__ W1, const float* __restrict__ b1,
    const float* __restrict__ W2, const float* __restrict__ gb2,
    const float* __restrict__ comb_W, const float* __restrict__ comb_b,
    const float* __restrict__ ln_g, const float* __restrict__ ln_b,
    float* __restrict__ out)
{
    __shared__ float sZt[256][NPB];
    __shared__ float sH2[2][128];
    __shared__ float sT1[2][128];
    __shared__ float sP1[4], sP2[4];
    __shared__ float sMu, sRs;
    const int t = threadIdx.x;
    const int half = t >> 7;
    const int j = t & 127;
    const float epsv = 1.f + eps_p[0];

    for (int pp=0; pp<NPB; pp+=2){
        const int nn = pp + half;
        const int n = blockIdx.x*NPB + nn;
        sH2[half][j] = epsv*x[(size_t)n*128 + j] + agg[(size_t)n*128 + j];
        sZt[j][nn] = gat_acc[(size_t)n*128 + j] + gat_b[j];
        __syncthreads();
        float acc = b1[j];
        #pragma unroll 8
        for (int k=0;k<128;k++) acc += sH2[half][k]*W1[k*128 + j];
        sT1[half][j] = fmaxf(acc, 0.f);
        __syncthreads();
        float acc2 = gb2[j];
        #pragma unroll 8
        for (int k=0;k<128;k++) acc2 += sT1[half][k]*W2[k*128 + j];
        sZt[128 + j][nn] = acc2;
        __syncthreads();
    }

    float z[NPB];
    const float cb = comb_b[t];
    #pragma unroll
    for (int nn=0;nn<NPB;nn++) z[nn] = cb;
    for (int k=0;k<256;k++){
        float w = comb_W[k*256 + t];
        float4 a = *(const float4*)&sZt[k][0];
        float4 b = *(const float4*)&sZt[k][4];
        z[0] += a.x*w; z[1] += a.y*w; z[2] += a.z*w; z[3] += a.w*w;
        z[4] += b.x*w; z[5] += b.y*w; z[6] += b.z*w; z[7] += b.w*w;
    }

    const float g  = ln_g[t];
    const float bb = ln_b[t];
    for (int nn=0;nn<NPB;nn++){
        const int n = blockIdx.x*NPB + nn;
        float zv = z[nn];
        float s1 = zv, s2 = zv*zv;
        #pragma unroll
        for (int off=32; off>=1; off>>=1){ s1 += __shfl_xor(s1,off,64); s2 += __shfl_xor(s2,off,64); }
        if ((t&63)==0){ sP1[t>>6]=s1; sP2[t>>6]=s2; }
        __syncthreads();
        if (t==0){
            float a1 = sP1[0]+sP1[1]+sP1[2]+sP1[3];
            float a2 = sP2[0]+sP2[1]+sP2[2]+sP2[3];
            float mu = a1*(1.f/256.f);
            float var = a2*(1.f/256.f) - mu*mu;
            sMu = mu; sRs = rsqrtf(var + 1e-5f);
        }
        __syncthreads();
        float r = (zv - sMu)*sRs*g + bb;
        out[(size_t)n*256 + t] = fmaxf(r, 0.f);
        __syncthreads();
    }
}

extern "C" void kernel_launch(void* const* d_in, const int* in_sizes, int n_in,
                              void* d_out, int out_size, void* d_ws, size_t ws_size,
                              hipStream_t stream)
{
    (void)in_sizes; (void)n_in; (void)out_size; (void)ws_size;
    const float* x           = (const float*)d_in[0];
    const int*   eidx_w      = (const int*)  d_in[1];
    const float* eattr       = (const float*)d_in[2];
    const int*   ety_w       = (const int*)  d_in[3];
    const float* gat_W       = (const float*)d_in[4];
    const float* gat_b       = (const float*)d_in[5];
    const float* gat_edge_W  = (const float*)d_in[6];
    const float* a_src       = (const float*)d_in[7];
    const float* a_dst       = (const float*)d_in[8];
    const float* a_edge      = (const float*)d_in[9];
    const float* gat_emb     = (const float*)d_in[10];
    const float* gine_emb    = (const float*)d_in[11];
    const float* gine_edge_W = (const float*)d_in[12];
    const float* gine_edge_b = (const float*)d_in[13];
    const float* gine_eps    = (const float*)d_in[14];
    const float* W1          = (const float*)d_in[15];
    const float* b1          = (const float*)d_in[16];
    const float* W2          = (const float*)d_in[17];
    const float* gb2         = (const float*)d_in[18];
    const float* comb_W      = (const float*)d_in[19];
    const float* comb_b      = (const float*)d_in[20];
    const float* ln_g        = (const float*)d_in[21];
    const float* ln_b        = (const float*)d_in[22];
    float* out = (float*)d_out;

    char* ws = (char*)d_ws;
    size_t off = 0;
    auto alloc = [&](size_t bytes)->void*{ void* p = ws + off; off += (bytes + 255)/256*256; return p; };
    size_t zero_start = off;
    int*      flags  = (int*)     alloc(256);
    int*      cnt    = (int*)     alloc((size_t)N_NODES*4);
    size_t zero_bytes = off - zero_start;
    int*      dstA   = (int*)     alloc((size_t)N_EDGES*4);
    int*      styA   = (int*)     alloc((size_t)N_EDGES*4);
    int*      rowp   = (int*)     alloc((size_t)(N_NODES+1)*4);
    int*      cursor = (int*)     alloc((size_t)N_NODES*4);
    int*      sty_s  = (int*)     alloc((size_t)N_EDGES*4);
    unsigned* evb    = (unsigned*)alloc((size_t)N_EDGES*64);
    float*    p_s    = (float*)   alloc((size_t)N_EDGES*8*4);
    unsigned* xhb    = (unsigned*)alloc((size_t)N_NODES*128*4);
    float*    a_s    = (float*)   alloc((size_t)N_NODES*8*4);
    float*    a_d    = (float*)   alloc((size_t)N_NODES*8*4);
    float*    Mt     = (float*)   alloc(32*8*4);
    float*    ATw    = (float*)   alloc(16*8*4);
    float*    Tw     = (float*)   alloc(16*128*4);
    float*    agg    = (float*)   alloc((size_t)N_NODES*128*4);
    float*    gacc   = (float*)   alloc((size_t)N_NODES*128*4);

    int n4 = (int)(zero_bytes/16);
    k0_zero<<<(n4+255)/256, 256, 0, stream>>>((float4*)(ws + zero_start), n4);
    kD_detect<<<512, 256, 0, stream>>>(eidx_w, ety_w, flags);
    kN_norm<<<1024, 256, 0, stream>>>(eidx_w, ety_w, flags, dstA, styA, cnt);
    kS_scan<<<1, 1024, 0, stream>>>(cnt, rowp, cursor);

    kM_pre<<<1, 256, 0, stream>>>(gat_edge_W, a_edge, gat_emb, Mt, ATw);
    kT_pre<<<16, 128, 0, stream>>>(gine_emb, gine_edge_W, gine_edge_b, Tw);
    k1_node_prep<<<N_NODES/8, 128, 0, stream>>>(x, gat_W, a_src, a_dst, xhb, a_s, a_d);

    kCE_edge<<<2500, 256, 0, stream>>>(eattr, dstA, styA, a_s, a_d, Mt, ATw,
                                       cursor, evb, p_s, sty_s);

    k3_gather<<<2500, 256, 0, stream>>>(xhb, evb, p_s, sty_s, rowp, Tw,
                                        gine_edge_W, agg, gacc);

    k4_final<<<N_NODES/NPB, 256, 0, stream>>>(x, agg, gacc, gat_b, gine_eps,
                                              W1, b1, W2, gb2, comb_W, comb_b,
                                              ln_g, ln_b, out);
}

// Round 8
// 532.761 us; speedup vs baseline: 2.7130x; 1.1788x over previous
//
#include <hip/hip_runtime.h>

#define N_NODES 20000
#define N_EDGES 640000

typedef _Float16 h2v __attribute__((ext_vector_type(2)));

__device__ __forceinline__ unsigned packh2(float a, float b){
    h2v v; v.x = (_Float16)a; v.y = (_Float16)b;
    return __builtin_bit_cast(unsigned, v);
}

#if __has_builtin(__builtin_amdgcn_fdot2)
__device__ __forceinline__ float fdot2f(h2v a, h2v b, float c){
    return __builtin_amdgcn_fdot2(a, b, c, false);
}
#else
__device__ __forceinline__ float fdot2f(h2v a, h2v b, float c){
    return c + (float)a.x*(float)b.x + (float)a.y*(float)b.y;
}
#endif

// ---------------- k0: zero flags + histogram counters ----------------
__global__ void k0_zero(float4* __restrict__ p, int n4){
    int i = blockIdx.x*blockDim.x + threadIdx.x;
    int stride = gridDim.x*blockDim.x;
    float4 z; z.x=0.f; z.y=0.f; z.z=0.f; z.w=0.f;
    for (; i<n4; i+=stride) p[i] = z;
}

// ---------------- kD: detect int32 vs int64 index buffers ----------------
__global__ void kD_detect(const int* __restrict__ eidx_w, const int* __restrict__ ety_w,
                          int* __restrict__ flags){
    int i = blockIdx.x*blockDim.x + threadIdx.x;
    int stride = gridDim.x*blockDim.x;
    int a0 = 0, a1 = 0;
    for (int w = 2*i+1; w < 2*N_EDGES; w += 2*stride) a0 |= eidx_w[w];
    for (int w = 2*i+1; w < N_EDGES;   w += 2*stride) a1 |= ety_w[w];
    if (a0) atomicOr(&flags[0], 1);
    if (a1) atomicOr(&flags[1], 1);
}

// ---------------- kN: normalize indices + fused dst histogram ----------------
__global__ void kN_norm(const int* __restrict__ eidx_w, const int* __restrict__ ety_w,
                        const int* __restrict__ flags,
                        int* __restrict__ dst, int* __restrict__ srcty,
                        int* __restrict__ cnt){
    int i = blockIdx.x*blockDim.x + threadIdx.x;
    int stride = gridDim.x*blockDim.x;
    const bool e32 = (flags[0] != 0);
    const bool t32 = (flags[1] != 0);
    for (int e = i; e < N_EDGES; e += stride){
        int s, d, t;
        if (e32){ s = eidx_w[e];   d = eidx_w[N_EDGES + e]; }
        else    { s = eidx_w[2*e]; d = eidx_w[2*N_EDGES + 2*e]; }
        t = t32 ? ety_w[e] : ety_w[2*e];
        s = min(max(s, 0), N_NODES-1);
        d = min(max(d, 0), N_NODES-1);
        t = min(max(t, 0), 15);
        dst[e] = d; srcty[e] = s | (t << 20);
        atomicAdd(&cnt[d], 1);
    }
}

// ---------------- kS: exclusive scan (4 elems/thread) -> row_ptr, cursor ----------------
__global__ __launch_bounds__(1024) void kS_scan(const int* __restrict__ cnt,
                                                int* __restrict__ row_ptr,
                                                int* __restrict__ cursor){
    __shared__ int sW[16];
    __shared__ int sWS[16];
    __shared__ int sbase;
    const int t = threadIdx.x, lane = t & 63, wv = t >> 6;
    if (t==0) sbase = 0;
    __syncthreads();
    for (int base=0; base<N_NODES; base+=4096){
        const int idx0 = base + t*4;
        int v0 = (idx0  <N_NODES) ? cnt[idx0  ] : 0;
        int v1 = (idx0+1<N_NODES) ? cnt[idx0+1] : 0;
        int v2 = (idx0+2<N_NODES) ? cnt[idx0+2] : 0;
        int v3 = (idx0+3<N_NODES) ? cnt[idx0+3] : 0;
        int p1 = v0+v1, p2 = p1+v2, tot = p2+v3;
        int xs = tot;
        #pragma unroll
        for (int off=1; off<64; off<<=1){
            int y = __shfl_up(xs, off, 64);
            if (lane >= off) xs += y;
        }
        if (lane==63) sW[wv] = xs;
        __syncthreads();
        if (t < 16){
            int wvv = sW[t], ws = wvv;
            #pragma unroll
            for (int off=1; off<16; off<<=1){
                int y = __shfl_up(ws, off, 16);
                if ((t&15) >= off) ws += y;
            }
            sWS[t] = ws - wvv;
        }
        __syncthreads();
        int ex = sbase + sWS[wv] + xs - tot;
        if (idx0  <N_NODES){ row_ptr[idx0  ]=ex;    cursor[idx0  ]=ex;    }
        if (idx0+1<N_NODES){ row_ptr[idx0+1]=ex+v0; cursor[idx0+1]=ex+v0; }
        if (idx0+2<N_NODES){ row_ptr[idx0+2]=ex+p1; cursor[idx0+2]=ex+p1; }
        if (idx0+3<N_NODES){ row_ptr[idx0+3]=ex+p2; cursor[idx0+3]=ex+p2; }
        __syncthreads();
        if (t==0) sbase += sWS[15] + sW[15];
        __syncthreads();
    }
    if (t==0) row_ptr[N_NODES] = sbase;
}

// ---------------- kPre: fused Mt/ATw (block 16) + Tw (blocks 0..15) ----------------
__global__ __launch_bounds__(256) void kPre(const float* __restrict__ gat_edge_W,
                                            const float* __restrict__ a_edge,
                                            const float* __restrict__ gat_emb,
                                            const float* __restrict__ gine_emb,
                                            const float* __restrict__ gine_edge_W,
                                            const float* __restrict__ gine_edge_b,
                                            float* __restrict__ Mt, float* __restrict__ ATw,
                                            float* __restrict__ Tw){
    const int t = threadIdx.x;
    if (blockIdx.x < 16){
        if (t < 128){
            const int tyv = blockIdx.x;
            float acc = gine_edge_b[t];
            #pragma unroll
            for (int d=0;d<32;d++) acc += gine_emb[tyv*32+d]*gine_edge_W[d*128+t];
            Tw[tyv*128+t] = acc;
        }
        return;
    }
    __shared__ float sM[32*8];
    const int d = t>>3, hh = t&7;
    float acc = 0.f;
    #pragma unroll
    for (int c=0;c<16;c++) acc += gat_edge_W[d*128 + hh*16 + c]*a_edge[hh*16 + c];
    sM[d*8+hh] = acc; Mt[hh*32 + d] = acc;
    __syncthreads();
    if (t < 128){
        int tyv = t>>3, h2 = t&7;
        float a = 0.f;
        #pragma unroll
        for (int dd=0;dd<32;dd++) a += gat_emb[tyv*32+dd]*sM[dd*8+h2];
        ATw[tyv*8+h2] = a;
    }
}

// ---------------- k1: h = x@gat_W (8 nodes/block), pack xhb (f16x2), a_s, a_d ----------------
__global__ __launch_bounds__(128) void k1_node_prep(
    const float* __restrict__ x, const float* __restrict__ gat_W,
    const float* __restrict__ a_src, const float* __restrict__ a_dst,
    unsigned* __restrict__ xhb, float* __restrict__ as_out, float* __restrict__ ad_out)
{
    __shared__ float sX[8][128];
    __shared__ float sH[128];
    const int t = threadIdx.x;
    const int base = blockIdx.x*8;
    const float4* xin = (const float4*)(x + (size_t)base*128);
    float4* sx4 = (float4*)&sX[0][0];
    for (int i=t;i<256;i+=128) sx4[i] = xin[i];
    __syncthreads();
    float acc[8] = {0,0,0,0,0,0,0,0};
    for (int k=0;k<128;k++){
        float w = gat_W[k*128 + t];
        #pragma unroll
        for (int nn=0;nn<8;nn++) acc[nn] += sX[nn][k]*w;
    }
    const float asv = a_src[t], advv = a_dst[t];
    #pragma unroll
    for (int nn=0;nn<8;nn++){
        const int n = base + nn;
        float vs = acc[nn]*asv, vd = acc[nn]*advv;
        #pragma unroll
        for (int off=8; off>=1; off>>=1){ vs += __shfl_xor(vs,off,16); vd += __shfl_xor(vd,off,16); }
        if ((t&15)==0){ as_out[n*8 + (t>>4)] = vs; ad_out[n*8 + (t>>4)] = vd; }
        __syncthreads();               // protect sH from previous nn's readers
        sH[t] = acc[nn];
        __syncthreads();
        if (t < 64){
            xhb[(size_t)n*128 + t] = packh2(sX[nn][2*t], sX[nn][2*t+1]);
        } else {
            int i = t - 64;
            xhb[(size_t)n*128 + 64 + i] = packh2(sH[2*i], sH[2*i+1]);
        }
    }
}

// ---------------- kCE: fused CSR-scatter + edge precompute (evb f16x2, p) ----------------
__global__ __launch_bounds__(256) void kCE_edge(
    const float* __restrict__ eattr,
    const int* __restrict__ dstA, const int* __restrict__ styA,
    const float* __restrict__ a_s, const float* __restrict__ a_d,
    const float* __restrict__ Mt, const float* __restrict__ ATw,
    int* __restrict__ cursor,
    unsigned* __restrict__ evb, float* __restrict__ p_s, int* __restrict__ sty_s)
{
    __shared__ float sEv[32][36];
    __shared__ float sMt[8][36];
    __shared__ float sAT[16*8];
    __shared__ int sPos[32];
    const int t = threadIdx.x;
    sMt[t>>5][t&31] = Mt[t];
    if (t < 128) sAT[t] = ATw[t];
    const int et = t>>3, q = t&7;
    for (int base = blockIdx.x*32; base < N_EDGES; base += gridDim.x*32){
        __syncthreads();   // protect sEv/sPos from previous iteration's readers
        const int e = base + et;
        float4 f = ((const float4*)eattr)[(size_t)e*8 + q];
        *(float4*)&sEv[et][q*4] = f;
        const int d = dstA[e];
        const int sty = styA[e];
        if (q==0) sPos[et] = atomicAdd(&cursor[d], 1);
        __syncthreads();
        const int pos = sPos[et];
        ((uint2*)evb)[(size_t)pos*8 + q] = make_uint2(packh2(f.x,f.y), packh2(f.z,f.w));
        float acc = 0.f;
        #pragma unroll
        for (int m=0;m<8;m++){
            float4 ev4 = *(const float4*)&sEv[et][m*4];
            float4 m4  = *(const float4*)&sMt[q][m*4];
            acc += ev4.x*m4.x + ev4.y*m4.y + ev4.z*m4.z + ev4.w*m4.w;
        }
        const int srcn = sty & 0xFFFFF;
        const int tyv = ((unsigned)sty)>>20;
        float lg = a_s[srcn*8+q] + a_d[d*8+q] + acc + sAT[tyv*8+q];
        lg = (lg>0.f) ? lg : 0.2f*lg;
        p_s[(size_t)pos*8 + q] = __expf(lg);
        if (q==0) sty_s[pos] = sty;
    }
}

// ---------------- k3: persistent gather — scalar-broadcast ev, no shfl ----------------
__global__ __launch_bounds__(256) void k3_gather(
    const unsigned* __restrict__ xhb, const unsigned* __restrict__ evb,
    const float* __restrict__ p_s, const int* __restrict__ sty_s,
    const int* __restrict__ row_ptr,
    const float* __restrict__ Tw, const float* __restrict__ gine_W,
    float* __restrict__ agg, float* __restrict__ gacc)
{
    __shared__ float sT[16*128];
    const int t = threadIdx.x;
    for (int i=t;i<2048;i+=256) sT[i]=Tw[i];
    const int lane = t & 63;
    const int j0 = 2*lane;
    const int hh = lane >> 3;            // head of channels (j0, j0+1)
    unsigned w0p[16], w1p[16];
    #pragma unroll
    for (int m=0;m<16;m++){
        w0p[m] = packh2(gine_W[(2*m)*128 + j0],   gine_W[(2*m+1)*128 + j0]);
        w1p[m] = packh2(gine_W[(2*m)*128 + j0+1], gine_W[(2*m+1)*128 + j0+1]);
    }
    __syncthreads();
    const int nwaves = gridDim.x*4;
    for (int d = blockIdx.x*4 + (t>>6); d < N_NODES; d += nwaves){
        const int row = row_ptr[d], end = row_ptr[d+1];
        float accA0=0.f, accA1=0.f, accG0=0.f, accG1=0.f, ps=0.f;
        if (row < end){
            // software-pipeline the wave-uniform sty load one edge ahead
            int sty_n = sty_s[__builtin_amdgcn_readfirstlane(row)];
            for (int pos = row; pos < end; pos++){
                const int sty = sty_n;
                if (pos+1 < end) sty_n = sty_s[__builtin_amdgcn_readfirstlane(pos+1)];
                const int posu = __builtin_amdgcn_readfirstlane(pos);
                const int srcn = sty & 0xFFFFF;
                const int ty = ((unsigned)sty)>>20;
                // wave-uniform ev fetch (SMEM/K$ path; no shfl)
                const uint4* evp = (const uint4*)(evb + (size_t)posu*16);
                uint4 ea = evp[0], eb = evp[1], ec = evp[2], ed = evp[3];
                unsigned xp = xhb[(size_t)srcn*128 + lane];
                unsigned hp = xhb[(size_t)srcn*128 + 64 + lane];
                float p = p_s[(size_t)posu*8 + hh];
                float2 tt = ((const float2*)sT)[ty*64 + lane];
                float ep0 = tt.x, ep1 = tt.y;
                unsigned uu[16] = {ea.x,ea.y,ea.z,ea.w, eb.x,eb.y,eb.z,eb.w,
                                   ec.x,ec.y,ec.z,ec.w, ed.x,ed.y,ed.z,ed.w};
                #pragma unroll
                for (int m=0;m<16;m++){
                    h2v ev = __builtin_bit_cast(h2v, uu[m]);
                    ep0 = fdot2f(ev, __builtin_bit_cast(h2v, w0p[m]), ep0);
                    ep1 = fdot2f(ev, __builtin_bit_cast(h2v, w1p[m]), ep1);
                }
                h2v xv = __builtin_bit_cast(h2v, xp);
                h2v hv = __builtin_bit_cast(h2v, hp);
                accA0 += fmaxf((float)xv.x + ep0, 0.f);
                accA1 += fmaxf((float)xv.y + ep1, 0.f);
                accG0 += p*(float)hv.x;
                accG1 += p*(float)hv.y;
                ps += p;
            }
        }
        float inv = 1.f/(ps + 1e-16f);
        ((float2*)agg )[(size_t)d*64 + lane] = make_float2(accA0, accA1);
        ((float2*)gacc)[(size_t)d*64 + lane] = make_float2(accG0*inv, accG1*inv);
    }
}

// ---------------- k4: final node kernel (GINE MLP ×4/half + comb + LN + ReLU) ----------------
#define NPB 8
__global__ __launch_bounds__(256) void k4_final(
    const float* __restrict__ x, const float* __restrict__ agg, const float* __restrict__ gat_acc,
    const float* __restrict__ gat_b, const float* __restrict__ eps_p,
    const float* __restrict__ W1, const float* __restrict__ b1,
    const float* __restrict__ W2, const float* __restrict__ gb2,
    const float* __restrict__ comb_W, const float* __restrict__ comb_b,
    const float* __restrict__ ln_g, const float* __restrict__ ln_b,
    float* __restrict__ out)
{
    __shared__ float sZt[256][NPB];      // 8 KB
    __shared__ float sH2[2][128][4];     // 4 KB, k-major x node
    __shared__ float sT1[2][128][4];     // 4 KB
    __shared__ float sP1[4], sP2[4];
    __shared__ float sMu, sRs;
    const int t = threadIdx.x;
    const int half = t >> 7;
    const int j = t & 127;
    const float epsv = 1.f + eps_p[0];

    // stage: each half owns nodes half*4 .. half*4+3
    {
        float hq[4];
        #pragma unroll
        for (int q=0;q<4;q++){
            const int nn = half*4 + q;
            const int n = blockIdx.x*NPB + nn;
            hq[q] = epsv*x[(size_t)n*128 + j] + agg[(size_t)n*128 + j];
            sZt[j][nn] = gat_acc[(size_t)n*128 + j] + gat_b[j];
        }
        *(float4*)&sH2[half][j][0] = make_float4(hq[0],hq[1],hq[2],hq[3]);
    }
    __syncthreads();
    {
        float acc[4];
        const float b1j = b1[j];
        #pragma unroll
        for (int q=0;q<4;q++) acc[q] = b1j;
        for (int k=0;k<128;k++){
            float w = W1[k*128 + j];
            float4 hv = *(const float4*)&sH2[half][k][0];
            acc[0] += hv.x*w; acc[1] += hv.y*w; acc[2] += hv.z*w; acc[3] += hv.w*w;
        }
        *(float4*)&sT1[half][j][0] = make_float4(fmaxf(acc[0],0.f), fmaxf(acc[1],0.f),
                                                 fmaxf(acc[2],0.f), fmaxf(acc[3],0.f));
    }
    __syncthreads();
    {
        float acc[4];
        const float b2j = gb2[j];
        #pragma unroll
        for (int q=0;q<4;q++) acc[q] = b2j;
        for (int k=0;k<128;k++){
            float w = W2[k*128 + j];
            float4 tv = *(const float4*)&sT1[half][k][0];
            acc[0] += tv.x*w; acc[1] += tv.y*w; acc[2] += tv.z*w; acc[3] += tv.w*w;
        }
        #pragma unroll
        for (int q=0;q<4;q++) sZt[128 + j][half*4 + q] = acc[q];
    }
    __syncthreads();

    float z[NPB];
    const float cb = comb_b[t];
    #pragma unroll
    for (int nn=0;nn<NPB;nn++) z[nn] = cb;
    for (int k=0;k<256;k++){
        float w = comb_W[k*256 + t];
        float4 a = *(const float4*)&sZt[k][0];
        float4 b = *(const float4*)&sZt[k][4];
        z[0] += a.x*w; z[1] += a.y*w; z[2] += a.z*w; z[3] += a.w*w;
        z[4] += b.x*w; z[5] += b.y*w; z[6] += b.z*w; z[7] += b.w*w;
    }

    const float g  = ln_g[t];
    const float bb = ln_b[t];
    for (int nn=0;nn<NPB;nn++){
        const int n = blockIdx.x*NPB + nn;
        float zv = z[nn];
        float s1 = zv, s2 = zv*zv;
        #pragma unroll
        for (int off=32; off>=1; off>>=1){ s1 += __shfl_xor(s1,off,64); s2 += __shfl_xor(s2,off,64); }
        if ((t&63)==0){ sP1[t>>6]=s1; sP2[t>>6]=s2; }
        __syncthreads();
        if (t==0){
            float a1 = sP1[0]+sP1[1]+sP1[2]+sP1[3];
            float a2 = sP2[0]+sP2[1]+sP2[2]+sP2[3];
            float mu = a1*(1.f/256.f);
            float var = a2*(1.f/256.f) - mu*mu;
            sMu = mu; sRs = rsqrtf(var + 1e-5f);
        }
        __syncthreads();
        float r = (zv - sMu)*sRs*g + bb;
        out[(size_t)n*256 + t] = fmaxf(r, 0.f);
        __syncthreads();
    }
}

extern "C" void kernel_launch(void* const* d_in, const int* in_sizes, int n_in,
                              void* d_out, int out_size, void* d_ws, size_t ws_size,
                              hipStream_t stream)
{
    (void)in_sizes; (void)n_in; (void)out_size; (void)ws_size;
    const float* x           = (const float*)d_in[0];
    const int*   eidx_w      = (const int*)  d_in[1];
    const float* eattr       = (const float*)d_in[2];
    const int*   ety_w       = (const int*)  d_in[3];
    const float* gat_W       = (const float*)d_in[4];
    const float* gat_b       = (const float*)d_in[5];
    const float* gat_edge_W  = (const float*)d_in[6];
    const float* a_src       = (const float*)d_in[7];
    const float* a_dst       = (const float*)d_in[8];
    const float* a_edge      = (const float*)d_in[9];
    const float* gat_emb     = (const float*)d_in[10];
    const float* gine_emb    = (const float*)d_in[11];
    const float* gine_edge_W = (const float*)d_in[12];
    const float* gine_edge_b = (const float*)d_in[13];
    const float* gine_eps    = (const float*)d_in[14];
    const float* W1          = (const float*)d_in[15];
    const float* b1          = (const float*)d_in[16];
    const float* W2          = (const float*)d_in[17];
    const float* gb2         = (const float*)d_in[18];
    const float* comb_W      = (const float*)d_in[19];
    const float* comb_b      = (const float*)d_in[20];
    const float* ln_g        = (const float*)d_in[21];
    const float* ln_b        = (const float*)d_in[22];
    float* out = (float*)d_out;

    char* ws = (char*)d_ws;
    size_t off = 0;
    auto alloc = [&](size_t bytes)->void*{ void* p = ws + off; off += (bytes + 255)/256*256; return p; };
    size_t zero_start = off;
    int*      flags  = (int*)     alloc(256);
    int*      cnt    = (int*)     alloc((size_t)N_NODES*4);
    size_t zero_bytes = off - zero_start;
    int*      dstA   = (int*)     alloc((size_t)N_EDGES*4);
    int*      styA   = (int*)     alloc((size_t)N_EDGES*4);
    int*      rowp   = (int*)     alloc((size_t)(N_NODES+1)*4);
    int*      cursor = (int*)     alloc((size_t)N_NODES*4);
    int*      sty_s  = (int*)     alloc((size_t)N_EDGES*4);
    unsigned* evb    = (unsigned*)alloc((size_t)N_EDGES*64);
    float*    p_s    = (float*)   alloc((size_t)N_EDGES*8*4);
    unsigned* xhb    = (unsigned*)alloc((size_t)N_NODES*128*4);
    float*    a_s    = (float*)   alloc((size_t)N_NODES*8*4);
    float*    a_d    = (float*)   alloc((size_t)N_NODES*8*4);
    float*    Mt     = (float*)   alloc(32*8*4);
    float*    ATw    = (float*)   alloc(16*8*4);
    float*    Tw     = (float*)   alloc(16*128*4);
    float*    agg    = (float*)   alloc((size_t)N_NODES*128*4);
    float*    gacc   = (float*)   alloc((size_t)N_NODES*128*4);

    int n4 = (int)(zero_bytes/16);
    k0_zero<<<(n4+255)/256, 256, 0, stream>>>((float4*)(ws + zero_start), n4);
    kD_detect<<<512, 256, 0, stream>>>(eidx_w, ety_w, flags);
    kN_norm<<<1024, 256, 0, stream>>>(eidx_w, ety_w, flags, dstA, styA, cnt);
    kS_scan<<<1, 1024, 0, stream>>>(cnt, rowp, cursor);

    kPre<<<17, 256, 0, stream>>>(gat_edge_W, a_edge, gat_emb, gine_emb,
                                 gine_edge_W, gine_edge_b, Mt, ATw, Tw);
    k1_node_prep<<<N_NODES/8, 128, 0, stream>>>(x, gat_W, a_src, a_dst, xhb, a_s, a_d);

    kCE_edge<<<2500, 256, 0, stream>>>(eattr, dstA, styA, a_s, a_d, Mt, ATw,
                                       cursor, evb, p_s, sty_s);

    k3_gather<<<2500, 256, 0, stream>>>(xhb, evb, p_s, sty_s, rowp, Tw,
                                        gine_edge_W, agg, gacc);

    k4_final<<<N_NODES/NPB, 256, 0, stream>>>(x, agg, gacc, gat_b, gine_eps,
                                              W1, b1, W2, gb2, comb_W, comb_b,
                                              ln_g, ln_b, out);
}